// Round 1
// baseline (447.793 us; speedup 1.0000x reference)
//
#include <hip/hip_runtime.h>
#include <math.h>

#define B_ 64
#define C_ 256
#define H_ 16
#define W_ 16
#define NEG_ 16
#define PRED_ 5
#define EPS_ 1e-11f

// ws layout in floats:
//   Zp: [16384][256]  (rows r=(h*16+w)*64+b, cols i)      off 0
//   Cp: [16384][256]  (same layout, from c)               off 4194304
//   Y : [14336][256]  (per-k projection, reused)          off 8388608
//   totals: [256]                                         off 12058624
#define ZP_F  0
#define CP_F  4194304
#define Y_F   8388608
#define TOT_F 12058624

// ---------------- transpose: [b*256+i][h*16+w] -> [(h*16+w)*64+b][i] ----------------
// Plain 16384x256 -> 256x16384 transpose (out[q][p] = in[p][q]).
__global__ __launch_bounds__(256) void transpose_zc(
    const float* __restrict__ z, const float* __restrict__ c,
    float* __restrict__ Zp, float* __restrict__ Cp) {
  __shared__ float tile[32][33];
  const float* in = blockIdx.z ? c : z;
  float* out = blockIdx.z ? Cp : Zp;
  int p0 = blockIdx.x * 32;   // p in [0,16384)
  int q0 = blockIdx.y * 32;   // q in [0,256)
  int tx = threadIdx.x, ty = threadIdx.y;  // (32,8)
#pragma unroll
  for (int r = 0; r < 32; r += 8)
    tile[ty + r][tx] = in[(size_t)(p0 + ty + r) * 256 + q0 + tx];
  __syncthreads();
#pragma unroll
  for (int r = 0; r < 32; r += 8)
    out[(size_t)(q0 + ty + r) * 16384 + p0 + tx] = tile[tx][ty + r];
}

// ---------------- GEMM: Y[m][o] = sum_i A[m][i] * Wm[o][i] ----------------
// A row-major [M][256], Wm row-major [256][256]; 64x64 block tile, BK=16.
__global__ __launch_bounds__(256) void gemm_proj(
    const float* __restrict__ A, const float* __restrict__ Wm,
    float* __restrict__ Y) {
  __shared__ float As[16][65];
  __shared__ float Ws[16][65];
  const int n0 = blockIdx.x * 64;
  const int m0 = blockIdx.y * 64;
  const int t = threadIdx.x;
  const int row = t >> 2;   // 0..63
  const int seg = t & 3;    // float4 segment within 16-wide K slab
  const int tx = t & 15, ty = t >> 4;
  float acc[4][4] = {};
  for (int k0 = 0; k0 < 256; k0 += 16) {
    float4 a = *(const float4*)&A[(size_t)(m0 + row) * 256 + k0 + seg * 4];
    float4 w = *(const float4*)&Wm[(size_t)(n0 + row) * 256 + k0 + seg * 4];
    __syncthreads();
    As[seg * 4 + 0][row] = a.x; As[seg * 4 + 1][row] = a.y;
    As[seg * 4 + 2][row] = a.z; As[seg * 4 + 3][row] = a.w;
    Ws[seg * 4 + 0][row] = w.x; Ws[seg * 4 + 1][row] = w.y;
    Ws[seg * 4 + 2][row] = w.z; Ws[seg * 4 + 3][row] = w.w;
    __syncthreads();
#pragma unroll
    for (int kk = 0; kk < 16; ++kk) {
      float av[4], wv[4];
#pragma unroll
      for (int i = 0; i < 4; ++i) av[i] = As[kk][ty * 4 + i];
#pragma unroll
      for (int j = 0; j < 4; ++j) wv[j] = Ws[kk][tx * 4 + j];
#pragma unroll
      for (int i = 0; i < 4; ++i)
#pragma unroll
        for (int j = 0; j < 4; ++j)
          acc[i][j] = fmaf(av[i], wv[j], acc[i][j]);
    }
  }
#pragma unroll
  for (int i = 0; i < 4; ++i) {
    float4 v = make_float4(acc[i][0], acc[i][1], acc[i][2], acc[i][3]);
    *(float4*)&Y[(size_t)(m0 + ty * 4 + i) * 256 + n0 + tx * 4] = v;
  }
}

// ---------------- scoring: one wave per row m ----------------
__global__ __launch_bounds__(256) void score_step(
    const float* __restrict__ Y, const float* __restrict__ Cp,
    const int* __restrict__ ridx, float* __restrict__ pl,
    float* __restrict__ totals, int M, int off, float scale) {
  int wid = (int)((blockIdx.x * (size_t)blockDim.x + threadIdx.x) >> 6);
  int lane = threadIdx.x & 63;
  if (wid >= M) return;
  const int m = wid;
  const float4 cv = ((const float4*)(Cp + (size_t)m * 256))[lane];
  const float4 zv = ((const float4*)(Y + (size_t)m * 256))[lane];
  float p = cv.x * zv.x + cv.y * zv.y + cv.z * zv.z + cv.w * zv.w;
#pragma unroll
  for (int s = 32; s; s >>= 1) p += __shfl_xor(p, s, 64);
  const float mainv = p;
  float mx = mainv;
  float negv[NEG_];
#pragma unroll
  for (int n = 0; n < NEG_; ++n) {
    int idx = ridx[(size_t)m * NEG_ + n];
    const float4 yv = ((const float4*)(Y + (size_t)idx * 256))[lane];
    float q = cv.x * yv.x + cv.y * yv.y + cv.z * yv.z + cv.w * yv.w;
#pragma unroll
    for (int s = 32; s; s >>= 1) q += __shfl_xor(q, s, 64);
    negv[n] = q;
    mx = fmaxf(mx, q);
  }
  float num = __expf(mainv - mx);
  float se = num;
#pragma unroll
  for (int n = 0; n < NEG_; ++n) se += __expf(negv[n] - mx);
  float loss = -logf(num / se + EPS_);
  if (lane == 0) {
    int b = m & 63, w = (m >> 6) & 15, h = m >> 10;
    atomicAdd(&pl[b * 256 + (h + off) * 16 + w], loss);
    atomicAdd(&pl[b * 256 + h * 16 + w], loss);
    atomicAdd(&totals[m & 255], loss * scale);
  }
}

// ---------------- finalize: counts + total reduction ----------------
__global__ __launch_bounds__(256) void finalize_k(
    const float* __restrict__ totals, float* __restrict__ out) {
  __shared__ float red[256];
  int t = threadIdx.x;
  int h = t >> 4;
  float cnt = 0.f;
#pragma unroll
  for (int off = 2; off <= 6; ++off)
    cnt += (h >= off ? 1.f : 0.f) + (h <= 15 - off ? 1.f : 0.f);
  out[1 + 16384 + t] = cnt;
  red[t] = totals[t];
  __syncthreads();
  for (int s = 128; s; s >>= 1) {
    if (t < s) red[t] += red[t + s];
    __syncthreads();
  }
  if (t == 0) out[0] = red[0];
}

extern "C" void kernel_launch(void* const* d_in, const int* in_sizes, int n_in,
                              void* d_out, int out_size, void* d_ws, size_t ws_size,
                              hipStream_t stream) {
  const float* z  = (const float*)d_in[0];
  const float* c  = (const float*)d_in[1];
  const float* Wk = (const float*)d_in[2];
  const int* ridx[PRED_] = {
    (const int*)d_in[3], (const int*)d_in[4], (const int*)d_in[5],
    (const int*)d_in[6], (const int*)d_in[7]};
  float* out = (float*)d_out;
  float* ws = (float*)d_ws;
  float* Zp = ws + ZP_F;
  float* Cp = ws + CP_F;
  float* Y  = ws + Y_F;
  float* totals = ws + TOT_F;

  hipMemsetAsync(d_out, 0, (size_t)out_size * sizeof(float), stream);
  hipMemsetAsync(totals, 0, 256 * sizeof(float), stream);

  transpose_zc<<<dim3(512, 8, 2), dim3(32, 8), 0, stream>>>(z, c, Zp, Cp);

  for (int k = 1; k <= PRED_; ++k) {
    const int off = k + 1;           // SKIP=1
    const int Hk = H_ - off;
    const int M = Hk * W_ * B_;      // Hk*1024
    gemm_proj<<<dim3(4, Hk * 16), 256, 0, stream>>>(
        Zp + (size_t)off * 1024 * 256, Wk + (size_t)(k - 1) * 256 * 256, Y);
    const float scale = 1.0f / (5.0f * (float)(B_ * Hk * W_));
    score_step<<<dim3((M + 3) / 4), 256, 0, stream>>>(
        Y, Cp, ridx[k - 1], out + 1, totals, M, off, scale);
  }

  finalize_k<<<1, 256, 0, stream>>>(totals, out);
}

// Round 3
// 305.254 us; speedup vs baseline: 1.4670x; 1.4670x over previous
//
#include <hip/hip_runtime.h>
#include <hip/hip_bf16.h>
#include <math.h>

#define B_ 64
#define C_ 256
#define H_ 16
#define W_ 16
#define NEG_ 16
#define PRED_ 5
#define EPS_ 1e-11f

typedef __attribute__((ext_vector_type(8))) short bf16x8;
typedef __attribute__((ext_vector_type(4))) float f32x4;

static __device__ __forceinline__ unsigned short f2bu(float f) {
  __hip_bfloat16 h = __float2bfloat16(f);
  return *(unsigned short*)&h;
}

// ws layout (bytes), all zeroed in-graph before use:
//   Zp  bf16 [16384][256] : 0          (8388608)   rows r=(h*16+w)*64+b
//   Cp  f32  [16384][256] : 8388608    (16777216)
//   Wb  bf16 [5][256][256]: 25165824   (655360)
//   Y   f32  [14336][256] : 25821184   (14680064)
//   Lk  f32  [5][14336]   : 40501248   (286720)
//   part f32 [280]        : 40787968   (1120)
#define WS_USED 40789088

// ---------------- transpose: [b*256+i][h*16+w] -> [(h*16+w)*64+b][i] ----------------
// z -> Zp (bf16), c -> Cp (f32)
__global__ __launch_bounds__(256) void transpose_zc(
    const float* __restrict__ z, const float* __restrict__ c,
    unsigned short* __restrict__ Zp, float* __restrict__ Cp) {
  __shared__ float tile[32][33];
  const float* in = blockIdx.z ? c : z;
  int p0 = blockIdx.x * 32;   // p in [0,16384)
  int q0 = blockIdx.y * 32;   // q in [0,256)
  int tx = threadIdx.x, ty = threadIdx.y;  // (32,8)
#pragma unroll
  for (int r = 0; r < 32; r += 8)
    tile[ty + r][tx] = in[(size_t)(p0 + ty + r) * 256 + q0 + tx];
  __syncthreads();
  if (blockIdx.z) {
#pragma unroll
    for (int r = 0; r < 32; r += 8)
      Cp[(size_t)(q0 + ty + r) * 16384 + p0 + tx] = tile[tx][ty + r];
  } else {
#pragma unroll
    for (int r = 0; r < 32; r += 8)
      Zp[(size_t)(q0 + ty + r) * 16384 + p0 + tx] = f2bu(tile[tx][ty + r]);
  }
}

// ---------------- cast Wk (5*256*256 fp32) -> bf16 ----------------
__global__ __launch_bounds__(256) void cast_w(
    const float* __restrict__ Wk, unsigned short* __restrict__ Wb) {
  int i = blockIdx.x * 256 + threadIdx.x;   // 81920 threads, 4 elems each
  float4 v = ((const float4*)Wk)[i];
  ushort4 o;
  o.x = f2bu(v.x); o.y = f2bu(v.y); o.z = f2bu(v.z); o.w = f2bu(v.w);
  ((ushort4*)Wb)[i] = o;
}

// ---------------- MFMA GEMM: Y[m][o] = sum_i A[m][i] * W[o][i] ----------------
// A [M][256] bf16, W [256][256] bf16, Y fp32. Direct global fragment loads,
// 128x128 block tile, 4 waves of 64x64, 16x16x32 mfma.
__global__ __launch_bounds__(256) void gemm_mfma(
    const unsigned short* __restrict__ A, const unsigned short* __restrict__ Wm,
    float* __restrict__ Y) {
  const int t = threadIdx.x;
  const int wid = t >> 6, lane = t & 63;
  const int wm = wid >> 1, wn = wid & 1;
  const int l15 = lane & 15, quad = lane >> 4;
  const int m0 = blockIdx.y * 128 + wm * 64;
  const int n0 = blockIdx.x * 128 + wn * 64;
  const unsigned short* a0 = A + (size_t)(m0 + l15) * 256 + quad * 8;
  const unsigned short* b0 = Wm + (size_t)(n0 + l15) * 256 + quad * 8;
  f32x4 acc[4][4] = {};
  for (int k0 = 0; k0 < 256; k0 += 32) {
    bf16x8 af[4], bf[4];
#pragma unroll
    for (int tm = 0; tm < 4; ++tm)
      af[tm] = *(const bf16x8*)(a0 + tm * 16 * 256 + k0);
#pragma unroll
    for (int tn = 0; tn < 4; ++tn)
      bf[tn] = *(const bf16x8*)(b0 + tn * 16 * 256 + k0);
#pragma unroll
    for (int tm = 0; tm < 4; ++tm)
#pragma unroll
      for (int tn = 0; tn < 4; ++tn)
        acc[tm][tn] = __builtin_amdgcn_mfma_f32_16x16x32_bf16(
            af[tm], bf[tn], acc[tm][tn], 0, 0, 0);
  }
  // C/D layout: col = lane&15, row = quad*4 + r
#pragma unroll
  for (int tm = 0; tm < 4; ++tm)
#pragma unroll
    for (int tn = 0; tn < 4; ++tn)
#pragma unroll
      for (int r = 0; r < 4; ++r) {
        int row = m0 + tm * 16 + quad * 4 + r;
        int col = n0 + tn * 16 + l15;
        Y[(size_t)row * 256 + col] = acc[tm][tn][r];
      }
}

// ---------------- scoring: one wave per row m; writes Lk[m] (no atomics) ----------
__global__ __launch_bounds__(256) void score_step(
    const float* __restrict__ Y, const float* __restrict__ Cp,
    const int* __restrict__ ridx, float* __restrict__ Lk, int M) {
  int wid = (int)((blockIdx.x * (size_t)blockDim.x + threadIdx.x) >> 6);
  int lane = threadIdx.x & 63;
  if (wid >= M) return;
  const int m = wid;
  const float4 cv = ((const float4*)(Cp + (size_t)m * 256))[lane];
  const float4 zv = ((const float4*)(Y + (size_t)m * 256))[lane];
  float p = cv.x * zv.x + cv.y * zv.y + cv.z * zv.z + cv.w * zv.w;
#pragma unroll
  for (int s = 32; s; s >>= 1) p += __shfl_xor(p, s, 64);
  const float mainv = p;
  float mx = mainv;
  float negv[NEG_];
#pragma unroll
  for (int n = 0; n < NEG_; ++n) {
    int idx = ridx[(size_t)m * NEG_ + n];
    const float4 yv = ((const float4*)(Y + (size_t)idx * 256))[lane];
    float q = cv.x * yv.x + cv.y * yv.y + cv.z * yv.z + cv.w * yv.w;
#pragma unroll
    for (int s = 32; s; s >>= 1) q += __shfl_xor(q, s, 64);
    negv[n] = q;
    mx = fmaxf(mx, q);
  }
  float num = __expf(mainv - mx);
  float se = num;
#pragma unroll
  for (int n = 0; n < NEG_; ++n) se += __expf(negv[n] - mx);
  float loss = -logf(num / se + EPS_);
  if (lane == 0) Lk[m] = loss;
}

// ---------------- reduce Lk -> 280 scaled partials ----------------
__global__ __launch_bounds__(256) void reduce_lk(
    const float* __restrict__ Lk, float* __restrict__ part) {
  __shared__ float red[256];
  const int kk = blockIdx.y;          // 0..4  (k = kk+1)
  const int Hk = 14 - kk;
  const float scale = 1.0f / (5120.0f * (float)Hk);  // 1/(5*B*Hk*W)
  int e = blockIdx.x * 256 + threadIdx.x;            // 56*256 = 14336
  red[threadIdx.x] = Lk[kk * 14336 + e] * scale;     // tail entries are 0
  __syncthreads();
  for (int s = 128; s; s >>= 1) {
    if (threadIdx.x < s) red[threadIdx.x] += red[threadIdx.x + s];
    __syncthreads();
  }
  if (threadIdx.x == 0) part[kk * 56 + blockIdx.x] = red[0];
}

// ---------------- final total: sum 280 partials ----------------
__global__ __launch_bounds__(512) void final_total(
    const float* __restrict__ part, float* __restrict__ out) {
  __shared__ float red[512];
  int t = threadIdx.x;
  red[t] = (t < 280) ? part[t] : 0.0f;
  __syncthreads();
  for (int s = 256; s; s >>= 1) {
    if (t < s) red[t] += red[t + s];
    __syncthreads();
  }
  if (t == 0) out[0] = red[0];
}

// ---------------- patchwise loss + counts (pure gather, one store each) --------
__global__ __launch_bounds__(256) void finalize_pl(
    const float* __restrict__ Lk, float* __restrict__ out) {
  int idx = blockIdx.x * 256 + threadIdx.x;   // 16384 = b*256 + h*16 + w
  int b = idx >> 8, h = (idx >> 4) & 15, w = idx & 15;
  float v = 0.f;
#pragma unroll
  for (int kk = 0; kk < PRED_; ++kk) {
    int off = kk + 2;
    if (h >= off)       v += Lk[kk * 14336 + ((h - off) * 16 + w) * 64 + b];
    if (h <= 15 - off)  v += Lk[kk * 14336 + (h * 16 + w) * 64 + b];
  }
  out[1 + idx] = v;
  if (idx < 256) {
    int hh = idx >> 4;
    float cnt = 0.f;
#pragma unroll
    for (int off = 2; off <= 6; ++off)
      cnt += (hh >= off ? 1.f : 0.f) + (hh <= 15 - off ? 1.f : 0.f);
    out[1 + 16384 + idx] = cnt;
  }
}

extern "C" void kernel_launch(void* const* d_in, const int* in_sizes, int n_in,
                              void* d_out, int out_size, void* d_ws, size_t ws_size,
                              hipStream_t stream) {
  const float* z  = (const float*)d_in[0];
  const float* c  = (const float*)d_in[1];
  const float* Wk = (const float*)d_in[2];
  const int* ridx[PRED_] = {
    (const int*)d_in[3], (const int*)d_in[4], (const int*)d_in[5],
    (const int*)d_in[6], (const int*)d_in[7]};
  float* out = (float*)d_out;
  char* wsb = (char*)d_ws;
  unsigned short* Zp = (unsigned short*)(wsb);
  float*          Cp = (float*)(wsb + 8388608);
  unsigned short* Wb = (unsigned short*)(wsb + 25165824);
  float*          Y  = (float*)(wsb + 25821184);
  float*          Lk = (float*)(wsb + 40501248);
  float*          part = (float*)(wsb + 40787968);

  // Zero the entire used workspace in-graph: removes every possible
  // dependence on pre-launch ws state (harness poisons ws with 0xAA).
  hipMemsetAsync(d_ws, 0, WS_USED, stream);

  transpose_zc<<<dim3(512, 8, 2), dim3(32, 8), 0, stream>>>(z, c, Zp, Cp);
  cast_w<<<320, 256, 0, stream>>>(Wk, Wb);

  for (int k = 1; k <= PRED_; ++k) {
    const int off = k + 1;           // SKIP=1
    const int Hk = H_ - off;
    const int M = Hk * W_ * B_;      // Hk*1024
    gemm_mfma<<<dim3(2, Hk * 8), 256, 0, stream>>>(
        Zp + (size_t)off * 1024 * 256, Wb + (size_t)(k - 1) * 65536, Y);
    score_step<<<dim3(M / 4), 256, 0, stream>>>(
        Y, Cp, ridx[k - 1], Lk + (size_t)(k - 1) * 14336, M);
  }

  reduce_lk<<<dim3(56, PRED_), 256, 0, stream>>>(Lk, part);
  finalize_pl<<<64, 256, 0, stream>>>(Lk, out);
  final_total<<<1, 512, 0, stream>>>(part, out);
}

// Round 4
// 256.547 us; speedup vs baseline: 1.7455x; 1.1899x over previous
//
#include <hip/hip_runtime.h>
#include <hip/hip_bf16.h>
#include <math.h>

#define B_ 64
#define C_ 256
#define H_ 16
#define W_ 16
#define NEG_ 16
#define PRED_ 5
#define EPS_ 1e-11f

typedef __attribute__((ext_vector_type(8))) short bf16x8;
typedef __attribute__((ext_vector_type(4))) float f32x4;

static __device__ __forceinline__ float b2f(unsigned short u) {
  return __uint_as_float(((unsigned int)u) << 16);
}
static __device__ __forceinline__ unsigned short f2bu(float f) {
  __hip_bfloat16 h = __float2bfloat16(f);
  return *(unsigned short*)&h;
}

// ws layout (bytes):
//   Zp  bf16 [16384][256] : 0          (8388608)   rows r=(h*16+w)*64+b
//   Cp  f32  [16384][256] : 8388608    (16777216)
//   Wb  bf16 [5][256][256]: 25165824   (655360)
//   Yb  bf16 [14336][256] : 25821184   (7340032)
//   Lk  f32  [5][14336]   : 33161216   (286720)  <- ONLY region memset in-graph
//   part f32 [280]        : 33447936   (1120)
// Dataflow audit (why no other memset is needed): Zp/Cp fully written by
// transpose; Wb fully written by cast_w; Yb rows [0,M) written by gemm before
// score reads them (gather idx < M by construction of rand_idx); part fully
// written by reduce_lk before final_total. Only reduce_lk reads Lk tail rows
// [M,14336) -> Lk must be zeroed.

// ---------------- transpose: [b*256+i][h*16+w] -> [(h*16+w)*64+b][i] ----------------
__global__ __launch_bounds__(256) void transpose_zc(
    const float* __restrict__ z, const float* __restrict__ c,
    unsigned short* __restrict__ Zp, float* __restrict__ Cp) {
  __shared__ float tile[32][33];
  const float* in = blockIdx.z ? c : z;
  int p0 = blockIdx.x * 32;   // p in [0,16384)
  int q0 = blockIdx.y * 32;   // q in [0,256)
  int tx = threadIdx.x, ty = threadIdx.y;  // (32,8)
#pragma unroll
  for (int r = 0; r < 32; r += 8)
    tile[ty + r][tx] = in[(size_t)(p0 + ty + r) * 256 + q0 + tx];
  __syncthreads();
  if (blockIdx.z) {
#pragma unroll
    for (int r = 0; r < 32; r += 8)
      Cp[(size_t)(q0 + ty + r) * 16384 + p0 + tx] = tile[tx][ty + r];
  } else {
#pragma unroll
    for (int r = 0; r < 32; r += 8)
      Zp[(size_t)(q0 + ty + r) * 16384 + p0 + tx] = f2bu(tile[tx][ty + r]);
  }
}

// ---------------- cast Wk (5*256*256 fp32) -> bf16 ----------------
__global__ __launch_bounds__(256) void cast_w(
    const float* __restrict__ Wk, unsigned short* __restrict__ Wb) {
  int i = blockIdx.x * 256 + threadIdx.x;   // 81920 threads, 4 elems each
  float4 v = ((const float4*)Wk)[i];
  ushort4 o;
  o.x = f2bu(v.x); o.y = f2bu(v.y); o.z = f2bu(v.z); o.w = f2bu(v.w);
  ((ushort4*)Wb)[i] = o;
}

// ---------------- MFMA GEMM: Y[m][o] = sum_i A[m][i] * W[o][i] ----------------
// A [M][256] bf16, W [256][256] bf16, Y bf16 out. Direct global fragment
// loads, 128x128 block tile, 4 waves of 64x64, 16x16x32 mfma.
__global__ __launch_bounds__(256) void gemm_mfma(
    const unsigned short* __restrict__ A, const unsigned short* __restrict__ Wm,
    unsigned short* __restrict__ Y) {
  const int t = threadIdx.x;
  const int wid = t >> 6, lane = t & 63;
  const int wm = wid >> 1, wn = wid & 1;
  const int l15 = lane & 15, quad = lane >> 4;
  const int m0 = blockIdx.y * 128 + wm * 64;
  const int n0 = blockIdx.x * 128 + wn * 64;
  const unsigned short* a0 = A + (size_t)(m0 + l15) * 256 + quad * 8;
  const unsigned short* b0 = Wm + (size_t)(n0 + l15) * 256 + quad * 8;
  f32x4 acc[4][4] = {};
  for (int k0 = 0; k0 < 256; k0 += 32) {
    bf16x8 af[4], bf[4];
#pragma unroll
    for (int tm = 0; tm < 4; ++tm)
      af[tm] = *(const bf16x8*)(a0 + tm * 16 * 256 + k0);
#pragma unroll
    for (int tn = 0; tn < 4; ++tn)
      bf[tn] = *(const bf16x8*)(b0 + tn * 16 * 256 + k0);
#pragma unroll
    for (int tm = 0; tm < 4; ++tm)
#pragma unroll
      for (int tn = 0; tn < 4; ++tn)
        acc[tm][tn] = __builtin_amdgcn_mfma_f32_16x16x32_bf16(
            af[tm], bf[tn], acc[tm][tn], 0, 0, 0);
  }
  // C/D layout: col = lane&15, row = quad*4 + r
#pragma unroll
  for (int tm = 0; tm < 4; ++tm)
#pragma unroll
    for (int tn = 0; tn < 4; ++tn)
#pragma unroll
      for (int r = 0; r < 4; ++r) {
        int row = m0 + tm * 16 + quad * 4 + r;
        int col = n0 + tn * 16 + l15;
        Y[(size_t)row * 256 + col] = f2bu(acc[tm][tn][r]);
      }
}

// ---------------- scoring: one wave per row m; writes Lk[m] (no atomics) ----------
__global__ __launch_bounds__(256) void score_step(
    const unsigned short* __restrict__ Y, const float* __restrict__ Cp,
    const int* __restrict__ ridx, float* __restrict__ Lk, int M) {
  int wid = (int)((blockIdx.x * (size_t)blockDim.x + threadIdx.x) >> 6);
  int lane = threadIdx.x & 63;
  if (wid >= M) return;
  const int m = wid;
  const float4 cv = ((const float4*)(Cp + (size_t)m * 256))[lane];
  ushort4 zu = ((const ushort4*)(Y + (size_t)m * 256))[lane];
  float p = cv.x * b2f(zu.x) + cv.y * b2f(zu.y) + cv.z * b2f(zu.z) + cv.w * b2f(zu.w);
#pragma unroll
  for (int s = 32; s; s >>= 1) p += __shfl_xor(p, s, 64);
  const float mainv = p;
  float mx = mainv;
  float negv[NEG_];
#pragma unroll
  for (int n = 0; n < NEG_; ++n) {
    int idx = ridx[(size_t)m * NEG_ + n];
    ushort4 yu = ((const ushort4*)(Y + (size_t)idx * 256))[lane];
    float q = cv.x * b2f(yu.x) + cv.y * b2f(yu.y) + cv.z * b2f(yu.z) + cv.w * b2f(yu.w);
#pragma unroll
    for (int s = 32; s; s >>= 1) q += __shfl_xor(q, s, 64);
    negv[n] = q;
    mx = fmaxf(mx, q);
  }
  float num = __expf(mainv - mx);
  float se = num;
#pragma unroll
  for (int n = 0; n < NEG_; ++n) se += __expf(negv[n] - mx);
  float loss = -logf(num / se + EPS_);
  if (lane == 0) Lk[m] = loss;
}

// ---------------- reduce Lk -> 280 scaled partials ----------------
__global__ __launch_bounds__(256) void reduce_lk(
    const float* __restrict__ Lk, float* __restrict__ part) {
  __shared__ float red[256];
  const int kk = blockIdx.y;          // 0..4  (k = kk+1)
  const int Hk = 14 - kk;
  const float scale = 1.0f / (5120.0f * (float)Hk);  // 1/(5*B*Hk*W)
  int e = blockIdx.x * 256 + threadIdx.x;            // 56*256 = 14336
  red[threadIdx.x] = Lk[kk * 14336 + e] * scale;     // tail entries are 0
  __syncthreads();
  for (int s = 128; s; s >>= 1) {
    if (threadIdx.x < s) red[threadIdx.x] += red[threadIdx.x + s];
    __syncthreads();
  }
  if (threadIdx.x == 0) part[kk * 56 + blockIdx.x] = red[0];
}

// ---------------- final total: sum 280 partials ----------------
__global__ __launch_bounds__(512) void final_total(
    const float* __restrict__ part, float* __restrict__ out) {
  __shared__ float red[512];
  int t = threadIdx.x;
  red[t] = (t < 280) ? part[t] : 0.0f;
  __syncthreads();
  for (int s = 256; s; s >>= 1) {
    if (t < s) red[t] += red[t + s];
    __syncthreads();
  }
  if (t == 0) out[0] = red[0];
}

// ---------------- patchwise loss + counts (pure gather, one store each) --------
__global__ __launch_bounds__(256) void finalize_pl(
    const float* __restrict__ Lk, float* __restrict__ out) {
  int idx = blockIdx.x * 256 + threadIdx.x;   // 16384 = b*256 + h*16 + w
  int b = idx >> 8, h = (idx >> 4) & 15, w = idx & 15;
  float v = 0.f;
#pragma unroll
  for (int kk = 0; kk < PRED_; ++kk) {
    int off = kk + 2;
    if (h >= off)       v += Lk[kk * 14336 + ((h - off) * 16 + w) * 64 + b];
    if (h <= 15 - off)  v += Lk[kk * 14336 + (h * 16 + w) * 64 + b];
  }
  out[1 + idx] = v;
  if (idx < 256) {
    int hh = idx >> 4;
    float cnt = 0.f;
#pragma unroll
    for (int off = 2; off <= 6; ++off)
      cnt += (hh >= off ? 1.f : 0.f) + (hh <= 15 - off ? 1.f : 0.f);
    out[1 + 16384 + idx] = cnt;
  }
}

extern "C" void kernel_launch(void* const* d_in, const int* in_sizes, int n_in,
                              void* d_out, int out_size, void* d_ws, size_t ws_size,
                              hipStream_t stream) {
  const float* z  = (const float*)d_in[0];
  const float* c  = (const float*)d_in[1];
  const float* Wk = (const float*)d_in[2];
  const int* ridx[PRED_] = {
    (const int*)d_in[3], (const int*)d_in[4], (const int*)d_in[5],
    (const int*)d_in[6], (const int*)d_in[7]};
  float* out = (float*)d_out;
  char* wsb = (char*)d_ws;
  unsigned short* Zp = (unsigned short*)(wsb);
  float*          Cp = (float*)(wsb + 8388608);
  unsigned short* Wb = (unsigned short*)(wsb + 25165824);
  unsigned short* Yb = (unsigned short*)(wsb + 25821184);
  float*          Lk = (float*)(wsb + 33161216);
  float*          part = (float*)(wsb + 33447936);

  // Only Lk needs zeroing (reduce_lk reads tail rows [M,14336) per step).
  hipMemsetAsync(Lk, 0, 286720, stream);

  transpose_zc<<<dim3(512, 8, 2), dim3(32, 8), 0, stream>>>(z, c, Zp, Cp);
  cast_w<<<320, 256, 0, stream>>>(Wk, Wb);

  for (int k = 1; k <= PRED_; ++k) {
    const int off = k + 1;           // SKIP=1
    const int Hk = H_ - off;
    const int M = Hk * W_ * B_;      // Hk*1024
    gemm_mfma<<<dim3(2, Hk * 8), 256, 0, stream>>>(
        Zp + (size_t)off * 1024 * 256, Wb + (size_t)(k - 1) * 65536, Yb);
    score_step<<<dim3(M / 4), 256, 0, stream>>>(
        Yb, Cp, ridx[k - 1], Lk + (size_t)(k - 1) * 14336, M);
  }

  reduce_lk<<<dim3(56, PRED_), 256, 0, stream>>>(Lk, part);
  finalize_pl<<<64, 256, 0, stream>>>(Lk, out);
  final_total<<<1, 512, 0, stream>>>(part, out);
}

// Round 7
// 210.891 us; speedup vs baseline: 2.1233x; 1.2165x over previous
//
#include <hip/hip_runtime.h>
#include <hip/hip_bf16.h>
#include <math.h>

#define B_ 64
#define C_ 256
#define H_ 16
#define W_ 16
#define NEG_ 16
#define PRED_ 5
#define EPS_ 1e-11f
#define LDW 18   // 16x17 logit tile padded to 18

typedef __attribute__((ext_vector_type(8))) short bf16x8;
typedef __attribute__((ext_vector_type(4))) float f32x4;

static __device__ __forceinline__ unsigned short f2bu(float f) {
  __hip_bfloat16 h = __float2bfloat16(f);
  return *(unsigned short*)&h;
}

// ws layout (bytes):
//   Zp bf16 [16384][256] : 0         (8388608)  rows q*64+b; rows<2048 (h<2) unused
//   Cb bf16 [16384][256] : 8388608   (8388608)  rows>=14336 (h>=14) unused
//   Wb bf16 [5][256][256]: 16777216  (655360)
//   Yb bf16 [5][14336][256]: 17432576 (36700160) rows>=M_k unused per k
//   Lk f32  [5][14336]   : 54132736  (286720)   <- ONLY memset (reduce_lk reads tails)
//   part f32 [280]       : 54419456  (1120)
// Index spaces: input flat = p*256+q with p=b*256+i, q=h*16+w; output row =
// q*64+b (note q*16384+p == (q*64+b)*256+i since 16384=64*256). Pruning is on
// q (blockIdx.y): z needs q>=32, c needs q<224.

// ---- transpose+cast: in[p][q] -> out[q*64+b][i] (bf16) ----
__global__ __launch_bounds__(256) void transpose_zc(
    const float* __restrict__ z, const float* __restrict__ c,
    unsigned short* __restrict__ Zp, unsigned short* __restrict__ Cb) {
  __shared__ float tile[32][33];
  const float* in = blockIdx.z ? c : z;
  unsigned short* out = blockIdx.z ? Cb : Zp;
  int p0 = blockIdx.x * 32;                          // full [0,16384)
  int q0 = blockIdx.y * 32 + (blockIdx.z ? 0 : 32);  // z:[32,256) c:[0,224)
  int tx = threadIdx.x, ty = threadIdx.y;  // (32,8)
#pragma unroll
  for (int r = 0; r < 32; r += 8)
    tile[ty + r][tx] = in[(size_t)(p0 + ty + r) * 256 + q0 + tx];
  __syncthreads();
#pragma unroll
  for (int r = 0; r < 32; r += 8)
    out[(size_t)(q0 + ty + r) * 16384 + p0 + tx] = f2bu(tile[tx][ty + r]);
}

// ---- cast Wk (5*256*256 fp32) -> bf16 ----
__global__ __launch_bounds__(256) void cast_w(
    const float* __restrict__ Wk, unsigned short* __restrict__ Wb) {
  int i = blockIdx.x * 256 + threadIdx.x;
  float4 v = ((const float4*)Wk)[i];
  ushort4 o;
  o.x = f2bu(v.x); o.y = f2bu(v.y); o.z = f2bu(v.z); o.w = f2bu(v.w);
  ((ushort4*)Wb)[i] = o;
}

// ---- batched MFMA GEMM over all 5 k: Yb[k][m][o] = sum_i Zp[off*1024+m][i]*Wk[o][i] ----
__global__ __launch_bounds__(256) void gemm_all(
    const unsigned short* __restrict__ Zp, const unsigned short* __restrict__ Wb,
    unsigned short* __restrict__ Yb) {
  const int kk = blockIdx.z;          // k = kk+1, off = kk+2
  const int Mk = (14 - kk) * 1024;
  const int m0b = blockIdx.y * 128;
  if (m0b >= Mk) return;
  const unsigned short* A = Zp + (size_t)(kk + 2) * 1024 * 256;
  const unsigned short* Wm = Wb + (size_t)kk * 65536;
  unsigned short* Y = Yb + (size_t)kk * 14336 * 256;
  const int t = threadIdx.x;
  const int wid = t >> 6, lane = t & 63;
  const int wm = wid >> 1, wn = wid & 1;
  const int l15 = lane & 15, quad = lane >> 4;
  const int m0 = m0b + wm * 64;
  const int n0 = blockIdx.x * 128 + wn * 64;
  const unsigned short* a0 = A + (size_t)(m0 + l15) * 256 + quad * 8;
  const unsigned short* b0 = Wm + (size_t)(n0 + l15) * 256 + quad * 8;
  f32x4 acc[4][4] = {};
  for (int k0 = 0; k0 < 256; k0 += 32) {
    bf16x8 af[4], bf[4];
#pragma unroll
    for (int tm = 0; tm < 4; ++tm) af[tm] = *(const bf16x8*)(a0 + tm * 16 * 256 + k0);
#pragma unroll
    for (int tn = 0; tn < 4; ++tn) bf[tn] = *(const bf16x8*)(b0 + tn * 16 * 256 + k0);
#pragma unroll
    for (int tm = 0; tm < 4; ++tm)
#pragma unroll
      for (int tn = 0; tn < 4; ++tn)
        acc[tm][tn] = __builtin_amdgcn_mfma_f32_16x16x32_bf16(af[tm], bf[tn], acc[tm][tn], 0, 0, 0);
  }
#pragma unroll
  for (int tm = 0; tm < 4; ++tm)
#pragma unroll
    for (int tn = 0; tn < 4; ++tn)
#pragma unroll
      for (int r = 0; r < 4; ++r)
        Y[(size_t)(m0 + tm * 16 + quad * 4 + r) * 256 + n0 + tn * 16 + l15] =
            f2bu(acc[tm][tn][r]);
}

// ---- fused scoring for all 5 k via MFMA ----
__global__ __launch_bounds__(256) void score_all(
    const unsigned short* __restrict__ Yb, const unsigned short* __restrict__ Cb,
    const int* __restrict__ r1, const int* __restrict__ r2,
    const int* __restrict__ r3, const int* __restrict__ r4,
    const int* __restrict__ r5, float* __restrict__ Lk) {
  __shared__ float lds[4][16 * LDW];
  const int wv = threadIdx.x >> 6, lane = threadIdx.x & 63;
  const int gid = blockIdx.x * 4 + wv;   // 0..3839
  int kk, base;
  if (gid < 896)       { kk = 0; base = 0; }
  else if (gid < 1728) { kk = 1; base = 896; }
  else if (gid < 2496) { kk = 2; base = 1728; }
  else if (gid < 3200) { kk = 3; base = 2496; }
  else                 { kk = 4; base = 3200; }
  const int Mk = (14 - kk) * 1024;
  const int m0 = (gid - base) * 16;
  const int* ridx = kk == 0 ? r1 : kk == 1 ? r2 : kk == 2 ? r3 : kk == 3 ? r4 : r5;
  const unsigned short* Y = Yb + (size_t)kk * 14336 * 256;
  const int l15 = lane & 15, quad = lane >> 4;
  float* L = lds[wv];

  // A fragments: ctx rows m0..m0+15, full K=256
  const unsigned short* arow = Cb + (size_t)(m0 + l15) * 256 + quad * 8;
  bf16x8 af[8];
#pragma unroll
  for (int tv = 0; tv < 8; ++tv) af[tv] = *(const bf16x8*)(arow + tv * 32);

  // main chain: B = Y rows m0..m0+15; keep diagonal D[i][i]
  {
    const unsigned short* brow = Y + (size_t)(m0 + l15) * 256 + quad * 8;
    f32x4 acc = {};
#pragma unroll
    for (int tv = 0; tv < 8; ++tv)
      acc = __builtin_amdgcn_mfma_f32_16x16x32_bf16(
          af[tv], *(const bf16x8*)(brow + tv * 32), acc, 0, 0, 0);
#pragma unroll
    for (int r = 0; r < 4; ++r)
      if (l15 == quad * 4 + r) L[(quad * 4 + r) * LDW] = acc[r];
  }
  // neg chains: for row i, B = 16 gathered rows; keep row D[i][*].
  // idx clamped to [0,Mk): free insurance against a device fault from any
  // out-of-range index (reference guarantees in-range; clamp is identity then).
#pragma unroll
  for (int i = 0; i < 16; ++i) {
    const int m = m0 + i;
    int idx = ridx[m * NEG_ + l15];
    idx = idx < 0 ? 0 : (idx >= Mk ? Mk - 1 : idx);
    const unsigned short* brow = Y + (size_t)idx * 256 + quad * 8;
    f32x4 acc = {};
#pragma unroll
    for (int tv = 0; tv < 8; ++tv)
      acc = __builtin_amdgcn_mfma_f32_16x16x32_bf16(
          af[tv], *(const bf16x8*)(brow + tv * 32), acc, 0, 0, 0);
    if (quad == (i >> 2)) L[i * LDW + 1 + l15] = acc[i & 3];
  }
  __syncthreads();
  if (lane < 16) {
    const int m = m0 + lane;
    float mainv = L[lane * LDW];
    float mx = mainv;
    float nv[NEG_];
#pragma unroll
    for (int n = 0; n < NEG_; ++n) { nv[n] = L[lane * LDW + 1 + n]; mx = fmaxf(mx, nv[n]); }
    float num = __expf(mainv - mx);
    float se = num;
#pragma unroll
    for (int n = 0; n < NEG_; ++n) se += __expf(nv[n] - mx);
    Lk[kk * 14336 + m] = -logf(num / se + EPS_);
  }
}

// ---- reduce Lk -> 280 scaled partials ----
__global__ __launch_bounds__(256) void reduce_lk(
    const float* __restrict__ Lk, float* __restrict__ part) {
  __shared__ float red[256];
  const int kk = blockIdx.y;
  const float scale = 1.0f / (5120.0f * (float)(14 - kk));
  int e = blockIdx.x * 256 + threadIdx.x;
  red[threadIdx.x] = Lk[kk * 14336 + e] * scale;
  __syncthreads();
  for (int s = 128; s; s >>= 1) {
    if (threadIdx.x < s) red[threadIdx.x] += red[threadIdx.x + s];
    __syncthreads();
  }
  if (threadIdx.x == 0) part[kk * 56 + blockIdx.x] = red[0];
}

__global__ __launch_bounds__(512) void final_total(
    const float* __restrict__ part, float* __restrict__ out) {
  __shared__ float red[512];
  int t = threadIdx.x;
  red[t] = (t < 280) ? part[t] : 0.0f;
  __syncthreads();
  for (int s = 256; s; s >>= 1) {
    if (t < s) red[t] += red[t + s];
    __syncthreads();
  }
  if (t == 0) out[0] = red[0];
}

// ---- patchwise loss + counts (pure gather, each out element written once) ----
__global__ __launch_bounds__(256) void finalize_pl(
    const float* __restrict__ Lk, float* __restrict__ out) {
  int idx = blockIdx.x * 256 + threadIdx.x;   // b*256 + h*16 + w
  int b = idx >> 8, h = (idx >> 4) & 15, w = idx & 15;
  float v = 0.f;
#pragma unroll
  for (int kk = 0; kk < PRED_; ++kk) {
    int off = kk + 2;
    if (h >= off)      v += Lk[kk * 14336 + ((h - off) * 16 + w) * 64 + b];
    if (h <= 15 - off) v += Lk[kk * 14336 + (h * 16 + w) * 64 + b];
  }
  out[1 + idx] = v;
  if (idx < 256) {
    int hh = idx >> 4;
    float cnt = 0.f;
#pragma unroll
    for (int off = 2; off <= 6; ++off)
      cnt += (hh >= off ? 1.f : 0.f) + (hh <= 15 - off ? 1.f : 0.f);
    out[1 + 16384 + idx] = cnt;
  }
}

extern "C" void kernel_launch(void* const* d_in, const int* in_sizes, int n_in,
                              void* d_out, int out_size, void* d_ws, size_t ws_size,
                              hipStream_t stream) {
  const float* z  = (const float*)d_in[0];
  const float* c  = (const float*)d_in[1];
  const float* Wk = (const float*)d_in[2];
  float* out = (float*)d_out;
  char* wsb = (char*)d_ws;
  unsigned short* Zp = (unsigned short*)(wsb);
  unsigned short* Cb = (unsigned short*)(wsb + 8388608);
  unsigned short* Wb = (unsigned short*)(wsb + 16777216);
  unsigned short* Yb = (unsigned short*)(wsb + 17432576);
  float*          Lk = (float*)(wsb + 54132736);
  float*          part = (float*)(wsb + 54419456);

  hipMemsetAsync(Lk, 0, 286720, stream);
  transpose_zc<<<dim3(512, 7, 2), dim3(32, 8), 0, stream>>>(z, c, Zp, Cb);
  cast_w<<<320, 256, 0, stream>>>(Wk, Wb);
  gemm_all<<<dim3(2, 112, PRED_), 256, 0, stream>>>(Zp, Wb, Yb);
  score_all<<<960, 256, 0, stream>>>(
      Yb, Cb, (const int*)d_in[3], (const int*)d_in[4], (const int*)d_in[5],
      (const int*)d_in[6], (const int*)d_in[7], Lk);
  reduce_lk<<<dim3(56, PRED_), 256, 0, stream>>>(Lk, part);
  finalize_pl<<<64, 256, 0, stream>>>(Lk, out);
  final_total<<<1, 512, 0, stream>>>(part, out);
}

// Round 8
// 201.338 us; speedup vs baseline: 2.2241x; 1.0474x over previous
//
#include <hip/hip_runtime.h>
#include <hip/hip_bf16.h>
#include <math.h>

#define B_ 64
#define C_ 256
#define H_ 16
#define W_ 16
#define NEG_ 16
#define PRED_ 5
#define EPS_ 1e-11f
#define LDW 18   // 16x17 logit tile padded to 18

typedef __attribute__((ext_vector_type(8))) short bf16x8;
typedef __attribute__((ext_vector_type(4))) float f32x4;

static __device__ __forceinline__ unsigned short f2bu(float f) {
  __hip_bfloat16 h = __float2bfloat16(f);
  return *(unsigned short*)&h;
}

// ws layout (bytes):
//   Zp bf16 [16384][256] : 0         (8388608)  rows q*64+b; rows<2048 (h<2) unused
//   Cb bf16 [16384][256] : 8388608   (8388608)  rows>=14336 (h>=14) unused
//   Wb bf16 [5][256][256]: 16777216  (655360)
//   Yb bf16 [5][14336][256]: 17432576 (36700160) rows>=M_k unused per k
//   Lk f32  [5][14336]   : 54132736  (286720)   <- ONLY memset (reduce_lk reads tails)
//   part f32 [280]       : 54419456  (1120)

// ---- transpose+cast: in[p=b*256+i][q=h*16+w] -> out[q*64+b][i] (bf16) ----
__global__ __launch_bounds__(256) void transpose_zc(
    const float* __restrict__ z, const float* __restrict__ c,
    unsigned short* __restrict__ Zp, unsigned short* __restrict__ Cb) {
  __shared__ float tile[32][33];
  const float* in = blockIdx.z ? c : z;
  unsigned short* out = blockIdx.z ? Cb : Zp;
  int p0 = blockIdx.x * 32;                          // full [0,16384)
  int q0 = blockIdx.y * 32 + (blockIdx.z ? 0 : 32);  // z:[32,256) c:[0,224)
  int tx = threadIdx.x, ty = threadIdx.y;  // (32,8)
#pragma unroll
  for (int r = 0; r < 32; r += 8)
    tile[ty + r][tx] = in[(size_t)(p0 + ty + r) * 256 + q0 + tx];
  __syncthreads();
#pragma unroll
  for (int r = 0; r < 32; r += 8)
    out[(size_t)(q0 + ty + r) * 16384 + p0 + tx] = f2bu(tile[tx][ty + r]);
}

// ---- cast Wk (5*256*256 fp32) -> bf16 ----
__global__ __launch_bounds__(256) void cast_w(
    const float* __restrict__ Wk, unsigned short* __restrict__ Wb) {
  int i = blockIdx.x * 256 + threadIdx.x;
  float4 v = ((const float4*)Wk)[i];
  ushort4 o;
  o.x = f2bu(v.x); o.y = f2bu(v.y); o.z = f2bu(v.z); o.w = f2bu(v.w);
  ((ushort4*)Wb)[i] = o;
}

// ---- batched MFMA GEMM, register-double-buffered K loop ----
__global__ __launch_bounds__(256) void gemm_all(
    const unsigned short* __restrict__ Zp, const unsigned short* __restrict__ Wb,
    unsigned short* __restrict__ Yb) {
  const int kk = blockIdx.z;          // k = kk+1, off = kk+2
  const int Mk = (14 - kk) * 1024;
  const int m0b = blockIdx.y * 128;
  if (m0b >= Mk) return;
  const unsigned short* A = Zp + (size_t)(kk + 2) * 1024 * 256;
  const unsigned short* Wm = Wb + (size_t)kk * 65536;
  unsigned short* Y = Yb + (size_t)kk * 14336 * 256;
  const int t = threadIdx.x;
  const int wid = t >> 6, lane = t & 63;
  const int wm = wid >> 1, wn = wid & 1;
  const int l15 = lane & 15, quad = lane >> 4;
  const int m0 = m0b + wm * 64;
  const int n0 = blockIdx.x * 128 + wn * 64;
  const unsigned short* a0 = A + (size_t)(m0 + l15) * 256 + quad * 8;
  const unsigned short* b0 = Wm + (size_t)(n0 + l15) * 256 + quad * 8;
  f32x4 acc[4][4] = {};
  bf16x8 ac[4], bc[4], an[4], bn[4];
#pragma unroll
  for (int tm = 0; tm < 4; ++tm) ac[tm] = *(const bf16x8*)(a0 + tm * 16 * 256);
#pragma unroll
  for (int tn = 0; tn < 4; ++tn) bc[tn] = *(const bf16x8*)(b0 + tn * 16 * 256);
#pragma unroll
  for (int kb = 0; kb < 8; ++kb) {
    if (kb < 7) {
      const int k1 = (kb + 1) * 32;
#pragma unroll
      for (int tm = 0; tm < 4; ++tm) an[tm] = *(const bf16x8*)(a0 + tm * 16 * 256 + k1);
#pragma unroll
      for (int tn = 0; tn < 4; ++tn) bn[tn] = *(const bf16x8*)(b0 + tn * 16 * 256 + k1);
    }
#pragma unroll
    for (int tm = 0; tm < 4; ++tm)
#pragma unroll
      for (int tn = 0; tn < 4; ++tn)
        acc[tm][tn] = __builtin_amdgcn_mfma_f32_16x16x32_bf16(ac[tm], bc[tn], acc[tm][tn], 0, 0, 0);
#pragma unroll
    for (int tm = 0; tm < 4; ++tm) ac[tm] = an[tm];
#pragma unroll
    for (int tn = 0; tn < 4; ++tn) bc[tn] = bn[tn];
  }
#pragma unroll
  for (int tm = 0; tm < 4; ++tm)
#pragma unroll
    for (int tn = 0; tn < 4; ++tn)
#pragma unroll
      for (int r = 0; r < 4; ++r)
        Y[(size_t)(m0 + tm * 16 + quad * 4 + r) * 256 + n0 + tn * 16 + l15] =
            f2bu(acc[tm][tn][r]);
}

// ---- fused scoring: one block (4 waves) per 16-row group ----
// ctx tile staged in LDS once; af[8] resident in regs per wave; 17 chains
// split 5/4/4/4 across waves; gathered B fragments double-buffered.
__global__ __launch_bounds__(256) void score_all(
    const unsigned short* __restrict__ Yb, const unsigned short* __restrict__ Cb,
    const int* __restrict__ r1, const int* __restrict__ r2,
    const int* __restrict__ r3, const int* __restrict__ r4,
    const int* __restrict__ r5, float* __restrict__ Lk) {
  __shared__ unsigned short ctx[16 * 256];   // 8 KB
  __shared__ float L[16 * LDW];
  const int wv = threadIdx.x >> 6, lane = threadIdx.x & 63;
  const int gid = blockIdx.x;                // 0..3839
  int kk, base;
  if (gid < 896)       { kk = 0; base = 0; }
  else if (gid < 1728) { kk = 1; base = 896; }
  else if (gid < 2496) { kk = 2; base = 1728; }
  else if (gid < 3200) { kk = 3; base = 2496; }
  else                 { kk = 4; base = 3200; }
  const int Mk = (14 - kk) * 1024;
  const int m0 = (gid - base) * 16;
  const int* ridx = kk == 0 ? r1 : kk == 1 ? r2 : kk == 2 ? r3 : kk == 3 ? r4 : r5;
  const unsigned short* Y = Yb + (size_t)kk * 14336 * 256;
  const int l15 = lane & 15, quad = lane >> 4;

  // stage ctx rows m0..m0+15 (4096 shorts = 512 uint4), coalesced
  {
    const uint4* src = (const uint4*)(Cb + (size_t)m0 * 256);
    uint4* dst = (uint4*)ctx;
    dst[threadIdx.x] = src[threadIdx.x];
    dst[threadIdx.x + 256] = src[threadIdx.x + 256];
  }
  __syncthreads();

  // A fragments from LDS, once, resident across all chains
  bf16x8 af[8];
#pragma unroll
  for (int tv = 0; tv < 8; ++tv)
    af[tv] = *(const bf16x8*)(ctx + l15 * 256 + quad * 8 + tv * 32);

  // chain c: 0 = main (B rows m0..m0+15), c>=1 = neg i=c-1 (gathered rows)
  const int c0 = (wv == 0) ? 0 : (4 * wv + 1);
  const int nc = (wv == 0) ? 5 : 4;

  const unsigned short* bp;
  {
    const int c = c0;
    if (c == 0) bp = Y + (size_t)(m0 + l15) * 256 + quad * 8;
    else {
      int idx = ridx[(m0 + (c - 1)) * NEG_ + l15];
      idx = idx < 0 ? 0 : (idx >= Mk ? Mk - 1 : idx);
      bp = Y + (size_t)idx * 256 + quad * 8;
    }
  }
  bf16x8 bcur[8], bnxt[8];
#pragma unroll
  for (int tv = 0; tv < 8; ++tv) bcur[tv] = *(const bf16x8*)(bp + tv * 32);

  for (int j = 0; j < nc; ++j) {
    if (j + 1 < nc) {
      const int c = c0 + j + 1;    // >= 1 always (main is first)
      int idx = ridx[(m0 + (c - 1)) * NEG_ + l15];
      idx = idx < 0 ? 0 : (idx >= Mk ? Mk - 1 : idx);
      const unsigned short* np = Y + (size_t)idx * 256 + quad * 8;
#pragma unroll
      for (int tv = 0; tv < 8; ++tv) bnxt[tv] = *(const bf16x8*)(np + tv * 32);
    }
    f32x4 acc = {};
#pragma unroll
    for (int tv = 0; tv < 8; ++tv)
      acc = __builtin_amdgcn_mfma_f32_16x16x32_bf16(af[tv], bcur[tv], acc, 0, 0, 0);
    const int c = c0 + j;
    if (c == 0) {
#pragma unroll
      for (int r = 0; r < 4; ++r)
        if (l15 == quad * 4 + r) L[(quad * 4 + r) * LDW] = acc[r];
    } else {
      const int i = c - 1;
      if (quad == (i >> 2)) L[i * LDW + 1 + l15] = acc[i & 3];
    }
#pragma unroll
    for (int tv = 0; tv < 8; ++tv) bcur[tv] = bnxt[tv];
  }
  __syncthreads();
  if (threadIdx.x < 16) {
    const int m = m0 + threadIdx.x;
    float mainv = L[threadIdx.x * LDW];
    float mx = mainv;
    float nv[NEG_];
#pragma unroll
    for (int n = 0; n < NEG_; ++n) {
      nv[n] = L[threadIdx.x * LDW + 1 + n];
      mx = fmaxf(mx, nv[n]);
    }
    float num = __expf(mainv - mx);
    float se = num;
#pragma unroll
    for (int n = 0; n < NEG_; ++n) se += __expf(nv[n] - mx);
    Lk[kk * 14336 + m] = -logf(num / se + EPS_);
  }
}

// ---- reduce Lk -> 280 scaled partials ----
__global__ __launch_bounds__(256) void reduce_lk(
    const float* __restrict__ Lk, float* __restrict__ part) {
  __shared__ float red[256];
  const int kk = blockIdx.y;
  const float scale = 1.0f / (5120.0f * (float)(14 - kk));
  int e = blockIdx.x * 256 + threadIdx.x;
  red[threadIdx.x] = Lk[kk * 14336 + e] * scale;
  __syncthreads();
  for (int s = 128; s; s >>= 1) {
    if (threadIdx.x < s) red[threadIdx.x] += red[threadIdx.x + s];
    __syncthreads();
  }
  if (threadIdx.x == 0) part[kk * 56 + blockIdx.x] = red[0];
}

__global__ __launch_bounds__(512) void final_total(
    const float* __restrict__ part, float* __restrict__ out) {
  __shared__ float red[512];
  int t = threadIdx.x;
  red[t] = (t < 280) ? part[t] : 0.0f;
  __syncthreads();
  for (int s = 256; s; s >>= 1) {
    if (t < s) red[t] += red[t + s];
    __syncthreads();
  }
  if (t == 0) out[0] = red[0];
}

// ---- patchwise loss + counts (pure gather, each out element written once) ----
__global__ __launch_bounds__(256) void finalize_pl(
    const float* __restrict__ Lk, float* __restrict__ out) {
  int idx = blockIdx.x * 256 + threadIdx.x;   // b*256 + h*16 + w
  int b = idx >> 8, h = (idx >> 4) & 15, w = idx & 15;
  float v = 0.f;
#pragma unroll
  for (int kk = 0; kk < PRED_; ++kk) {
    int off = kk + 2;
    if (h >= off)      v += Lk[kk * 14336 + ((h - off) * 16 + w) * 64 + b];
    if (h <= 15 - off) v += Lk[kk * 14336 + (h * 16 + w) * 64 + b];
  }
  out[1 + idx] = v;
  if (idx < 256) {
    int hh = idx >> 4;
    float cnt = 0.f;
#pragma unroll
    for (int off = 2; off <= 6; ++off)
      cnt += (hh >= off ? 1.f : 0.f) + (hh <= 15 - off ? 1.f : 0.f);
    out[1 + 16384 + idx] = cnt;
  }
}

extern "C" void kernel_launch(void* const* d_in, const int* in_sizes, int n_in,
                              void* d_out, int out_size, void* d_ws, size_t ws_size,
                              hipStream_t stream) {
  const float* z  = (const float*)d_in[0];
  const float* c  = (const float*)d_in[1];
  const float* Wk = (const float*)d_in[2];
  float* out = (float*)d_out;
  char* wsb = (char*)d_ws;
  unsigned short* Zp = (unsigned short*)(wsb);
  unsigned short* Cb = (unsigned short*)(wsb + 8388608);
  unsigned short* Wb = (unsigned short*)(wsb + 16777216);
  unsigned short* Yb = (unsigned short*)(wsb + 17432576);
  float*          Lk = (float*)(wsb + 54132736);
  float*          part = (float*)(wsb + 54419456);

  hipMemsetAsync(Lk, 0, 286720, stream);
  transpose_zc<<<dim3(512, 7, 2), dim3(32, 8), 0, stream>>>(z, c, Zp, Cb);
  cast_w<<<320, 256, 0, stream>>>(Wk, Wb);
  gemm_all<<<dim3(2, 112, PRED_), 256, 0, stream>>>(Zp, Wb, Yb);
  score_all<<<3840, 256, 0, stream>>>(
      Yb, Cb, (const int*)d_in[3], (const int*)d_in[4], (const int*)d_in[5],
      (const int*)d_in[6], (const int*)d_in[7], Lk);
  reduce_lk<<<dim3(56, PRED_), 256, 0, stream>>>(Lk, part);
  finalize_pl<<<64, 256, 0, stream>>>(Lk, out);
  final_total<<<1, 512, 0, stream>>>(part, out);
}